// Round 4
// baseline (530.214 us; speedup 1.0000x reference)
//
#include <hip/hip_runtime.h>

typedef unsigned short u16;
typedef __bf16 bf16x8 __attribute__((ext_vector_type(8)));
typedef float f32x4 __attribute__((ext_vector_type(4)));
typedef unsigned short u16x8 __attribute__((ext_vector_type(8)));

__device__ __forceinline__ float b2f(u16 b){ union{unsigned u; float f;} v; v.u=((unsigned)b)<<16; return v.f; }
__device__ __forceinline__ u16 f2b(float f){ unsigned u=__builtin_bit_cast(unsigned,f); return (u16)((u+0x7fffu+((u>>16)&1u))>>16); }
__device__ __forceinline__ float wred32(float v){
  #pragma unroll
  for(int off=16; off>0; off>>=1) v += __shfl_xor(v, off, 64);
  return v;
}
__device__ __forceinline__ void stOut(u16* p, float v){ *p = f2b(v); }
__device__ __forceinline__ void stOut(float* p, float v){ *p = v; }

// async global->LDS, 16B per lane: lane L writes ldsbase + L*16
__device__ __forceinline__ void gload_lds16(const void* g, void* l){
  __builtin_amdgcn_global_load_lds(
      (const __attribute__((address_space(1))) void*)g,
      (__attribute__((address_space(3))) void*)l, 16, 0, 0);
}

// reg-staged 8-elem store into LDS (fp32 source converted to bf16)
__device__ __forceinline__ void stageA8(u16* dst, const float* src){
  float4 a = *(const float4*)src;
  float4 b = *(const float4*)(src+4);
  ushort4 o0; o0.x=f2b(a.x); o0.y=f2b(a.y); o0.z=f2b(a.z); o0.w=f2b(a.w);
  ushort4 o1; o1.x=f2b(b.x); o1.y=f2b(b.y); o1.z=f2b(b.z); o1.w=f2b(b.w);
  *(ushort4*)dst = o0;
  *(ushort4*)(dst+4) = o1;
}

// ---------------- generic MFMA GEMM, z-batched: C_z[M,N] = act(A_z[M,K] @ Wt_z^T + bias_z) ----
// A bf16 (global_load_lds staging) or fp32 (reg-staged + converted). Wt bf16 [n][k], row stride K.
// Tiles BM=128, BN=64, BK=64. LDS LINEAR [r][64], XOR swizzle col ^= (r&7)<<3 (both-sides rule).
// MODE 0: +bias. MODE 1: relu(+bias). MODE 2: mult*sigmoid(+bias).
// DUAL: K split in half; first half reads A, second half reads A2 (both lda).
struct GP {
  const void* A[3];
  const void* A2;
  const u16*  Wt[3];
  const float* bias[3];
  void* C[3];
  const u16* mult;
  int lda, K, Nreal, ldc, ldm;
};

template<int MODE, typename OT, typename AT, bool DUAL>
__global__ __launch_bounds__(256) void gemm_k(GP p)
{
  const int z = blockIdx.z;
  const AT* __restrict__ A  = (const AT*)p.A[z];
  const AT* __restrict__ A2 = (const AT*)p.A2;
  const u16* __restrict__ Wt = p.Wt[z];
  const float* __restrict__ bias = p.bias[z];
  OT* __restrict__ C = (OT*)p.C[z];
  const int lda = p.lda, K = p.K, Nreal = p.Nreal, ldc = p.ldc, ldm = p.ldm;

  __shared__ __align__(16) u16 As[128*64];
  __shared__ __align__(16) u16 Bs[64*64];
  const int tid = threadIdx.x;
  const size_t m0 = (size_t)blockIdx.x * 128;
  const int n0 = blockIdx.y * 64;
  const int lane = tid & 63, w = tid >> 6;
  const int lr = lane & 15, quad = lane >> 4;
  const int wr = (w >> 1) * 64, wc = (w & 1) * 32;
  const int swz = (lr & 7) << 3;
  const int KH = K >> 1;

  f32x4 acc[4][2];
  #pragma unroll
  for(int i=0;i<4;++i)
    #pragma unroll
    for(int j=0;j<2;++j) acc[i][j] = (f32x4){0.f,0.f,0.f,0.f};

  for(int k0=0; k0<K; k0+=64){
    const AT* Ap = A;
    int kcol = k0;
    if (DUAL && k0 >= KH) { Ap = A2; kcol = k0 - KH; }

    if constexpr (__is_same(AT, u16)) {
      #pragma unroll
      for(int it=0; it<4; ++it){
        int cbase = it*256 + w*64;
        int ch = cbase + lane;
        int r = ch >> 3;
        int ce = ((ch & 7) * 8) ^ ((r & 7) << 3);   // inverse-swizzled source col (elems)
        gload_lds16(Ap + (m0+r)*(size_t)lda + kcol + ce, &As[cbase*8]);
      }
    } else {
      #pragma unroll
      for(int it=0; it<4; ++it){
        int ch = tid + 256*it; int r = ch>>3, s = (ch&7)*8;
        stageA8(&As[r*64 + (s ^ ((r&7)<<3))], Ap + (m0+r)*(size_t)lda + kcol + s);
      }
    }
    #pragma unroll
    for(int it=0; it<2; ++it){
      int cbase = it*256 + w*64;
      int ch = cbase + lane;
      int r = ch >> 3;
      int ce = ((ch & 7) * 8) ^ ((r & 7) << 3);
      gload_lds16(Wt + (size_t)(n0+r)*K + k0 + ce, &Bs[cbase*8]);
    }
    __syncthreads();
    #pragma unroll
    for(int kk=0; kk<64; kk+=32){
      bf16x8 af[4], bfr[2];
      #pragma unroll
      for(int i=0;i<4;++i)
        af[i]  = *(const bf16x8*)&As[(wr + i*16 + lr)*64 + ((kk + quad*8) ^ swz)];
      #pragma unroll
      for(int j=0;j<2;++j)
        bfr[j] = *(const bf16x8*)&Bs[(wc + j*16 + lr)*64 + ((kk + quad*8) ^ swz)];
      #pragma unroll
      for(int i=0;i<4;++i)
        #pragma unroll
        for(int j=0;j<2;++j)
          acc[i][j] = __builtin_amdgcn_mfma_f32_16x16x32_bf16(af[i], bfr[j], acc[i][j], 0, 0, 0);
    }
    __syncthreads();
  }
  // epilogue: D row = wr+i*16+quad*4+r, col = wc+j*16+lr
  #pragma unroll
  for(int j=0;j<2;++j){
    int col = n0 + wc + j*16 + lr;
    float bv = (col < Nreal) ? bias[col] : 0.f;
    #pragma unroll
    for(int i=0;i<4;++i){
      #pragma unroll
      for(int r=0;r<4;++r){
        size_t row = m0 + wr + i*16 + quad*4 + r;
        size_t ci = row*(size_t)ldc + col;
        float v = acc[i][j][r] + bv;
        if(MODE==1) v = fmaxf(v, 0.f);
        if(MODE==2){
          float mv = b2f(p.mult[row*(size_t)ldm + col]);
          v = mv * __builtin_amdgcn_rcpf(1.f + __expf(-v));
        }
        stOut(&C[ci], v);
      }
    }
  }
}

// ---------------- weight pre-transpose fp32->bf16 (+zero pad): dst[n*Kp+k] = src[k*N+n]
struct TPar { const float* src; u16* dst; int K, N, Kp, Np; };
struct TArgs { TPar p[8]; };
__global__ __launch_bounds__(256) void transpose_all(TArgs args){
  TPar p = args.p[blockIdx.y];
  int n = blockIdx.x;
  if (n >= p.Np) return;
  for (int k = threadIdx.x; k < p.Kp; k += 256){
    u16 v = 0;
    if (n < p.N && k < p.K) v = f2b(p.src[(size_t)k*p.N + n]);
    p.dst[(size_t)n*p.Kp + k] = v;
  }
}

// ---------------- row-wise middle. Wave covers 2 rows: 32 lanes x 8 elems per row.
__global__ __launch_bounds__(256) void mid_k(
    const u16* eb, const u16* ef, const u16* ep,
    const float* __restrict__ Wg, const float* __restrict__ bg,
    u16* common, u16* weighted)
{
  const int wid = threadIdx.x >> 6, lane = threadIdx.x & 63;
  const int half = lane >> 5, l5 = lane & 31;
  const size_t row = (size_t)blockIdx.x * 8 + wid*2 + half;
  const size_t base = row*256 + l5*8;

  u16x8 vb = *(const u16x8*)(eb + base);
  u16x8 vf = *(const u16x8*)(ef + base);
  u16x8 vp = *(const u16x8*)(ep + base);
  float fb[8], ff[8], fp[8];
  #pragma unroll
  for(int j=0;j<8;++j){ fb[j]=b2f(vb[j]); ff[j]=b2f(vf[j]); fp[j]=b2f(vp[j]); }

  float sb=0, sf=0, sp=0, d01=0, d02=0, d12=0, g0=0, g1=0, g2=0;
  #pragma unroll
  for(int j=0;j<8;++j){
    sb += fb[j]*fb[j]; sf += ff[j]*ff[j]; sp += fp[j]*fp[j];
    d01 += fb[j]*ff[j]; d02 += fb[j]*fp[j]; d12 += ff[j]*fp[j];
  }
  // weight generator: allc @ Wg, Wg is [768,3] fp32 row-major
  #pragma unroll
  for(int seg=0; seg<3; ++seg){
    const float* x = (seg==0) ? fb : (seg==1) ? ff : fp;
    const float* wg = Wg + ((size_t)seg*256 + l5*8)*3;   // 24 consecutive floats, 16B-aligned
    float wv[24];
    #pragma unroll
    for(int q=0;q<6;++q){
      float4 t = *(const float4*)(wg + q*4);
      wv[q*4+0]=t.x; wv[q*4+1]=t.y; wv[q*4+2]=t.z; wv[q*4+3]=t.w;
    }
    #pragma unroll
    for(int j=0;j<8;++j){
      g0 += x[j]*wv[j*3+0];
      g1 += x[j]*wv[j*3+1];
      g2 += x[j]*wv[j*3+2];
    }
  }
  sb=wred32(sb); sf=wred32(sf); sp=wred32(sp);
  d01=wred32(d01); d02=wred32(d02); d12=wred32(d12);
  g0=wred32(g0); g1=wred32(g1); g2=wred32(g2);

  float inb  = __builtin_amdgcn_rsqf(fmaxf(sb, 1e-24f));
  float invf = __builtin_amdgcn_rsqf(fmaxf(sf, 1e-24f));
  float inp  = __builtin_amdgcn_rsqf(fmaxf(sp, 1e-24f));
  float s01 = d01*inb*invf, s02 = d02*inb*inp, s12 = d12*invf*inp;

  g0 += bg[0]; g1 += bg[1]; g2 += bg[2];
  float gm = fmaxf(g0, fmaxf(g1, g2));
  float e0 = __expf(g0-gm), e1 = __expf(g1-gm), e2 = __expf(g2-gm);
  float res = __builtin_amdgcn_rcpf(e0+e1+e2);
  float fw0 = e0*res, fw1 = e1*res, fw2 = e2*res;

  bool p0 = s01 > 0.6f, p1 = s02 > 0.6f, p2 = s12 > 0.6f;
  bool has = p0 || p1 || p2;
  float mm = -__builtin_inff();
  if(p0) mm = fmaxf(mm, s01);
  if(p1) mm = fmaxf(mm, s02);
  if(p2) mm = fmaxf(mm, s12);
  if(!has) mm = 0.f;
  float q0 = p0 ? __expf(s01-mm) : 0.f;
  float q1 = p1 ? __expf(s02-mm) : 0.f;
  float q2 = p2 ? __expf(s12-mm) : 0.f;
  float rqs = __builtin_amdgcn_rcpf(fmaxf(q0+q1+q2, 1e-12f));
  float w0 = q0*rqs, w1 = q1*rqs, w2 = q2*rqs;

  u16x8 oc, ow;
  #pragma unroll
  for(int j=0;j<8;++j){
    float a = fb[j], b = ff[j], c = fp[j];
    float na = a*inb, nbv = b*invf, nc = c*inp;
    float c0 = (na*nbv > 0.6f) ? 0.5f*(a+b) : 0.f;
    float c1 = (na*nc  > 0.6f) ? 0.5f*(a+c) : 0.f;
    float c2 = (nbv*nc > 0.6f) ? 0.5f*(b+c) : 0.f;
    float sc = c0*w0 + c1*w1 + c2*w2;
    float cf = has ? sc : (a+b+c)*(1.f/3.f);
    float wv = a*fw0 + b*fw1 + c*fw2;
    oc[j] = f2b(cf); ow[j] = f2b(wv);
  }
  *(u16x8*)(common + base) = oc;       // in-place over ep
  *(u16x8*)(weighted + base) = ow;     // in-place over eb
}

extern "C" void kernel_launch(void* const* d_in, const int* in_sizes, int n_in,
                              void* d_out, int out_size, void* d_ws, size_t ws_size,
                              hipStream_t stream) {
  const float* brics = (const float*)d_in[0];
  const float* fg    = (const float*)d_in[1];
  const float* ph    = (const float*)d_in[2];
  const float* W1[3] = {(const float*)d_in[3], (const float*)d_in[7], (const float*)d_in[11]};
  const float* b1[3] = {(const float*)d_in[4], (const float*)d_in[8], (const float*)d_in[12]};
  const float* W2[3] = {(const float*)d_in[5], (const float*)d_in[9], (const float*)d_in[13]};
  const float* b2[3] = {(const float*)d_in[6], (const float*)d_in[10], (const float*)d_in[14]};
  const float* Wg = (const float*)d_in[15];
  const float* bg = (const float*)d_in[16];
  const float* We = (const float*)d_in[17];
  const float* be = (const float*)d_in[18];
  const float* Wf = (const float*)d_in[19];
  const float* bf = (const float*)d_in[20];
  float* out = (float*)d_out;

  const int M = in_sizes[0] / 256;   // 65536

  // ---- workspace carve ----
  char* wsp = (char*)d_ws;
  size_t off = 0;
  auto carve = [&](size_t elems)->u16* {
    u16* p = (u16*)(wsp + off);
    off += ((elems*sizeof(u16)) + 255) & ~(size_t)255;
    return p;
  };
  u16* xb0 = carve((size_t)M*256);   // enc0 (brics), then weighted (in-place)
  u16* xb1 = carve((size_t)M*256);   // enc1 (fg), then ce (gate out)
  u16* xb2 = carve((size_t)M*256);   // enc2 (ph), then common (in-place)
  u16* Wt1[3], *Wt2[3];
  for(int i=0;i<3;++i) Wt1[i] = carve(320*256);
  for(int i=0;i<3;++i) Wt2[i] = carve(256*320);
  u16* WtE = carve(256*256);
  u16* WtF = carve(256*512);         // full fused-output weight: [n=256][k=512]

  // hidden buffers: 3 separate if workspace allows (enables z-batched encoder GEMMs)
  size_t hb = (((size_t)M*320*sizeof(u16)) + 255) & ~(size_t)255;
  bool batched = (off + 3*hb) <= ws_size;
  u16* hh[3];
  hh[0] = (u16*)(wsp + off);
  hh[1] = batched ? (u16*)(wsp + off + hb)   : hh[0];
  hh[2] = batched ? (u16*)(wsp + off + 2*hb) : hh[0];
  (void)n_in; (void)out_size;

  // ---- 1. transpose/convert all weights ----
  TArgs ta;
  for(int i=0;i<3;++i){
    ta.p[i]   = {W1[i], Wt1[i], 256, 300, 256, 320};  // Wt1: [320][256]
    ta.p[3+i] = {W2[i], Wt2[i], 300, 256, 320, 256};  // Wt2: [256][320]
  }
  ta.p[6] = {We, WtE, 256, 256, 256, 256};
  ta.p[7] = {Wf, WtF, 512, 256, 512, 256};            // Wf: [512,256] -> WtF [256][512]
  transpose_all<<<dim3(512, 8), 256, 0, stream>>>(ta);

  // ---- 2. encoders: h_i = relu(x_i@W1+b1); enc_i = h_i@W2+b2 ----
  const float* xin[3] = {brics, fg, ph};
  u16* encp[3] = {xb0, xb1, xb2};
  if (batched) {
    GP g1{};
    for(int i=0;i<3;++i){ g1.A[i]=xin[i]; g1.Wt[i]=Wt1[i]; g1.bias[i]=b1[i]; g1.C[i]=hh[i]; }
    g1.lda=256; g1.K=256; g1.Nreal=300; g1.ldc=320;
    gemm_k<1,u16,float,false><<<dim3(M/128, 5, 3), 256, 0, stream>>>(g1);
    GP g2{};
    for(int i=0;i<3;++i){ g2.A[i]=hh[i]; g2.Wt[i]=Wt2[i]; g2.bias[i]=b2[i]; g2.C[i]=encp[i]; }
    g2.lda=320; g2.K=320; g2.Nreal=256; g2.ldc=256;
    gemm_k<0,u16,u16,false><<<dim3(M/128, 4, 3), 256, 0, stream>>>(g2);
  } else {
    for(int i=0;i<3;++i){
      GP g1{}; g1.A[0]=xin[i]; g1.Wt[0]=Wt1[i]; g1.bias[0]=b1[i]; g1.C[0]=hh[0];
      g1.lda=256; g1.K=256; g1.Nreal=300; g1.ldc=320;
      gemm_k<1,u16,float,false><<<dim3(M/128, 5, 1), 256, 0, stream>>>(g1);
      GP g2{}; g2.A[0]=hh[0]; g2.Wt[0]=Wt2[i]; g2.bias[0]=b2[i]; g2.C[0]=encp[i];
      g2.lda=320; g2.K=320; g2.Nreal=256; g2.ldc=256;
      gemm_k<0,u16,u16,false><<<dim3(M/128, 4, 1), 256, 0, stream>>>(g2);
    }
  }

  // ---- 3. row-wise middle: weighted -> xb0 (in place), common -> xb2 (in place) ----
  mid_k<<<M/8, 256, 0, stream>>>(xb0, xb1, xb2, Wg, bg, /*common=*/xb2, /*weighted=*/xb0);

  // ---- 4. gate: ce(xb1) = common * sigmoid(common@We + be) ----
  {
    GP gg{}; gg.A[0]=xb2; gg.Wt[0]=WtE; gg.bias[0]=be; gg.C[0]=xb1;
    gg.mult=xb2; gg.lda=256; gg.K=256; gg.Nreal=256; gg.ldc=256; gg.ldm=256;
    gemm_k<2,u16,u16,false><<<dim3(M/128, 4, 1), 256, 0, stream>>>(gg);
  }

  // ---- 5. fused output: out = [weighted | ce] @ WtF^T + bf  (single K=512 GEMM) ----
  {
    GP gf{}; gf.A[0]=xb0; gf.A2=xb1; gf.Wt[0]=WtF; gf.bias[0]=bf; gf.C[0]=out;
    gf.lda=256; gf.K=512; gf.Nreal=256; gf.ldc=256;
    gemm_k<0,float,u16,true><<<dim3(M/128, 4, 1), 256, 0, stream>>>(gf);
  }
}

// Round 5
// 497.461 us; speedup vs baseline: 1.0658x; 1.0658x over previous
//
#include <hip/hip_runtime.h>

typedef unsigned short u16;
typedef __bf16 bf16x8 __attribute__((ext_vector_type(8)));
typedef float f32x4 __attribute__((ext_vector_type(4)));
typedef unsigned short u16x8 __attribute__((ext_vector_type(8)));

__device__ __forceinline__ float b2f(u16 b){ union{unsigned u; float f;} v; v.u=((unsigned)b)<<16; return v.f; }
__device__ __forceinline__ u16 f2b(float f){ unsigned u=__builtin_bit_cast(unsigned,f); return (u16)((u+0x7fffu+((u>>16)&1u))>>16); }
__device__ __forceinline__ float wred32(float v){
  #pragma unroll
  for(int off=16; off>0; off>>=1) v += __shfl_xor(v, off, 64);
  return v;
}
__device__ __forceinline__ void stOut(u16* p, float v){ *p = f2b(v); }
__device__ __forceinline__ void stOut(float* p, float v){ *p = v; }

// async global->LDS, 16B per lane: lane L writes ldsbase + L*16
__device__ __forceinline__ void gload_lds16(const void* g, void* l){
  __builtin_amdgcn_global_load_lds(
      (const __attribute__((address_space(1))) void*)g,
      (__attribute__((address_space(3))) void*)l, 16, 0, 0);
}

// stage a [ROWS x 64] bf16 tile via global_load_lds; LDS linear, source carries inverse XOR
// swizzle (col ^= (r&7)<<3, in elements) so ds_read with the same XOR is conflict-free.
// PER = ROWS*8/512 chunks per thread (512-thread block).
template<int PER>
__device__ __forceinline__ void stage_tile_b16(const u16* __restrict__ base, int rstride,
                                               int kcol, u16* lds, int w, int lane){
  #pragma unroll
  for(int it=0; it<PER; ++it){
    int cbase = it*512 + w*64;
    int ch = cbase + lane;
    int r = ch >> 3;
    int ce = ((ch & 7) * 8) ^ ((r & 7) << 3);
    gload_lds16(base + (size_t)r*rstride + kcol + ce, lds + cbase*8);
  }
}

// fp32 A tile: T14 async split. Issue loads early (into regs), convert+ds_write late.
struct Af32Regs { float4 a0, b0, a1, b1; };
__device__ __forceinline__ void loadA_f32(Af32Regs& rg, const float* __restrict__ Ap,
                                          int lda, int kcol, int tid){
  {
    int ch = tid;       int r = ch>>3, s = (ch&7)*8;
    const float* src = Ap + (size_t)r*lda + kcol + s;
    rg.a0 = *(const float4*)src; rg.b0 = *(const float4*)(src+4);
  }
  {
    int ch = tid + 512; int r = ch>>3, s = (ch&7)*8;
    const float* src = Ap + (size_t)r*lda + kcol + s;
    rg.a1 = *(const float4*)src; rg.b1 = *(const float4*)(src+4);
  }
}
__device__ __forceinline__ void writeA_f32(const Af32Regs& rg, u16* As, int tid){
  {
    int ch = tid;       int r = ch>>3, s = (ch&7)*8;
    u16* dst = &As[r*64 + (s ^ ((r&7)<<3))];
    ushort4 o0{f2b(rg.a0.x),f2b(rg.a0.y),f2b(rg.a0.z),f2b(rg.a0.w)};
    ushort4 o1{f2b(rg.b0.x),f2b(rg.b0.y),f2b(rg.b0.z),f2b(rg.b0.w)};
    *(ushort4*)dst = o0; *(ushort4*)(dst+4) = o1;
  }
  {
    int ch = tid + 512; int r = ch>>3, s = (ch&7)*8;
    u16* dst = &As[r*64 + (s ^ ((r&7)<<3))];
    ushort4 o0{f2b(rg.a1.x),f2b(rg.a1.y),f2b(rg.a1.z),f2b(rg.a1.w)};
    ushort4 o1{f2b(rg.b1.x),f2b(rg.b1.y),f2b(rg.b1.z),f2b(rg.b1.w)};
    *(ushort4*)dst = o0; *(ushort4*)(dst+4) = o1;
  }
}

// ---------------- wide MFMA GEMM, z-batched: C_z[M, BN] = act(A_z[M,K] @ Wt_z^T + bias_z) ----
// One block covers the FULL N (BN = NWT*64): A fetched exactly once.
// 512 threads = 8 waves (2 row x 4 col); per wave 64 rows x NWT*16 cols.
// Double-buffered LDS; stage(t+1) issued BEFORE MFMA(t) so the barrier drain lands after compute.
// MODE 0: +bias. MODE 1: relu(+bias). MODE 2: mult*sigmoid(+bias).
// DUAL: K split in half; first half reads A, second half A2 (both lda).
struct GP {
  const void* A[3];
  const void* A2;
  const u16*  Wt[3];
  const float* bias[3];
  void* C[3];
  const u16* mult;
  int lda, K, Nreal, ldc, ldm;
};

template<int MODE, typename OT, typename AT, bool DUAL, int NWT>
__global__ __launch_bounds__(512, 2) void gemm_w(GP p)
{
  const int z = blockIdx.z;
  const AT* __restrict__ A  = (const AT*)p.A[z];
  const AT* __restrict__ A2 = (const AT*)p.A2;
  const u16* __restrict__ Wt = p.Wt[z];
  const float* __restrict__ bias = p.bias[z];
  OT* __restrict__ C = (OT*)p.C[z];
  const int lda = p.lda, K = p.K, ldc = p.ldc;

  __shared__ __align__(16) u16 As[2][128*64];
  __shared__ __align__(16) u16 Bs[2][NWT*64*64];

  const int tid = threadIdx.x;
  const size_t m0 = (size_t)blockIdx.x * 128;
  const int lane = tid & 63, w = tid >> 6;
  const int lr = lane & 15, quad = lane >> 4;
  const int wr = (w >> 2) * 64, wc = (w & 3) * (NWT*16);
  const int swz = (lr & 7) << 3;
  const int KH = K >> 1, NT = K >> 6;

  f32x4 acc[4][NWT];
  #pragma unroll
  for(int i=0;i<4;++i)
    #pragma unroll
    for(int j=0;j<NWT;++j) acc[i][j] = (f32x4){0.f,0.f,0.f,0.f};

  const AT* Ab1 = A + m0*(size_t)lda;
  const AT* Ab2 = DUAL ? (A2 + m0*(size_t)lda) : nullptr;

  // prologue: stage tile 0 into buf 0
  {
    if constexpr (__is_same(AT, u16)) {
      stage_tile_b16<2>((const u16*)Ab1, lda, 0, As[0], w, lane);
    } else {
      Af32Regs rg; loadA_f32(rg, (const float*)Ab1, lda, 0, tid);
      writeA_f32(rg, As[0], tid);
    }
    stage_tile_b16<NWT>(Wt, K, 0, Bs[0], w, lane);
  }
  __syncthreads();

  int cur = 0;
  for(int t=0; t<NT; ++t){
    const int knext = (t+1) << 6;
    const bool pf = (t+1) < NT;
    Af32Regs rg;
    if (pf){
      const AT* Ap = Ab1; int kc = knext;
      if (DUAL && knext >= KH) { Ap = Ab2; kc = knext - KH; }
      if constexpr (__is_same(AT, u16))
        stage_tile_b16<2>((const u16*)Ap, lda, kc, As[cur^1], w, lane);
      else
        loadA_f32(rg, (const float*)Ap, lda, kc, tid);   // issue early; write after MFMA
      stage_tile_b16<NWT>(Wt, K, knext, Bs[cur^1], w, lane);
    }
    #pragma unroll
    for(int kk=0; kk<64; kk+=32){
      bf16x8 af[4], bq[NWT];
      #pragma unroll
      for(int i=0;i<4;++i)
        af[i] = *(const bf16x8*)&As[cur][(wr + i*16 + lr)*64 + ((kk + quad*8) ^ swz)];
      #pragma unroll
      for(int j=0;j<NWT;++j)
        bq[j] = *(const bf16x8*)&Bs[cur][(wc + j*16 + lr)*64 + ((kk + quad*8) ^ swz)];
      #pragma unroll
      for(int i=0;i<4;++i)
        #pragma unroll
        for(int j=0;j<NWT;++j)
          acc[i][j] = __builtin_amdgcn_mfma_f32_16x16x32_bf16(af[i], bq[j], acc[i][j], 0, 0, 0);
    }
    if constexpr (!__is_same(AT, u16)) { if (pf) writeA_f32(rg, As[cur^1], tid); }
    __syncthreads();
    cur ^= 1;
  }

  // epilogue: D row = wr+i*16+quad*4+r, col = wc+j*16+lr
  #pragma unroll
  for(int j=0;j<NWT;++j){
    int col = wc + j*16 + lr;
    float bv = (col < p.Nreal) ? bias[col] : 0.f;
    #pragma unroll
    for(int i=0;i<4;++i){
      #pragma unroll
      for(int r=0;r<4;++r){
        size_t row = m0 + wr + i*16 + quad*4 + r;
        size_t ci = row*(size_t)ldc + col;
        float v = acc[i][j][r] + bv;
        if(MODE==1) v = fmaxf(v, 0.f);
        if(MODE==2){
          float mv = b2f(p.mult[row*(size_t)p.ldm + col]);
          v = mv * __builtin_amdgcn_rcpf(1.f + __expf(-v));
        }
        stOut(&C[ci], v);
      }
    }
  }
}

// ---------------- weight pre-transpose fp32->bf16 (+zero pad): dst[n*Kp+k] = src[k*N+n]
struct TPar { const float* src; u16* dst; int K, N, Kp, Np; };
struct TArgs { TPar p[8]; };
__global__ __launch_bounds__(256) void transpose_all(TArgs args){
  TPar p = args.p[blockIdx.y];
  int n = blockIdx.x;
  if (n >= p.Np) return;
  for (int k = threadIdx.x; k < p.Kp; k += 256){
    u16 v = 0;
    if (n < p.N && k < p.K) v = f2b(p.src[(size_t)k*p.N + n]);
    p.dst[(size_t)n*p.Kp + k] = v;
  }
}

// ---------------- row-wise middle. Wave covers 2 rows: 32 lanes x 8 elems per row.
__global__ __launch_bounds__(256) void mid_k(
    const u16* eb, const u16* ef, const u16* ep,
    const float* __restrict__ Wg, const float* __restrict__ bg,
    u16* common, u16* weighted)
{
  const int wid = threadIdx.x >> 6, lane = threadIdx.x & 63;
  const int half = lane >> 5, l5 = lane & 31;
  const size_t row = (size_t)blockIdx.x * 8 + wid*2 + half;
  const size_t base = row*256 + l5*8;

  u16x8 vb = *(const u16x8*)(eb + base);
  u16x8 vf = *(const u16x8*)(ef + base);
  u16x8 vp = *(const u16x8*)(ep + base);
  float fb[8], ff[8], fp[8];
  #pragma unroll
  for(int j=0;j<8;++j){ fb[j]=b2f(vb[j]); ff[j]=b2f(vf[j]); fp[j]=b2f(vp[j]); }

  float sb=0, sf=0, sp=0, d01=0, d02=0, d12=0, g0=0, g1=0, g2=0;
  #pragma unroll
  for(int j=0;j<8;++j){
    sb += fb[j]*fb[j]; sf += ff[j]*ff[j]; sp += fp[j]*fp[j];
    d01 += fb[j]*ff[j]; d02 += fb[j]*fp[j]; d12 += ff[j]*fp[j];
  }
  // weight generator: allc @ Wg, Wg is [768,3] fp32 row-major
  #pragma unroll
  for(int seg=0; seg<3; ++seg){
    const float* x = (seg==0) ? fb : (seg==1) ? ff : fp;
    const float* wg = Wg + ((size_t)seg*256 + l5*8)*3;   // 24 consecutive floats, 16B-aligned
    float wv[24];
    #pragma unroll
    for(int q=0;q<6;++q){
      float4 t = *(const float4*)(wg + q*4);
      wv[q*4+0]=t.x; wv[q*4+1]=t.y; wv[q*4+2]=t.z; wv[q*4+3]=t.w;
    }
    #pragma unroll
    for(int j=0;j<8;++j){
      g0 += x[j]*wv[j*3+0];
      g1 += x[j]*wv[j*3+1];
      g2 += x[j]*wv[j*3+2];
    }
  }
  sb=wred32(sb); sf=wred32(sf); sp=wred32(sp);
  d01=wred32(d01); d02=wred32(d02); d12=wred32(d12);
  g0=wred32(g0); g1=wred32(g1); g2=wred32(g2);

  float inb  = __builtin_amdgcn_rsqf(fmaxf(sb, 1e-24f));
  float invf = __builtin_amdgcn_rsqf(fmaxf(sf, 1e-24f));
  float inp  = __builtin_amdgcn_rsqf(fmaxf(sp, 1e-24f));
  float s01 = d01*inb*invf, s02 = d02*inb*inp, s12 = d12*invf*inp;

  g0 += bg[0]; g1 += bg[1]; g2 += bg[2];
  float gm = fmaxf(g0, fmaxf(g1, g2));
  float e0 = __expf(g0-gm), e1 = __expf(g1-gm), e2 = __expf(g2-gm);
  float res = __builtin_amdgcn_rcpf(e0+e1+e2);
  float fw0 = e0*res, fw1 = e1*res, fw2 = e2*res;

  bool p0 = s01 > 0.6f, p1 = s02 > 0.6f, p2 = s12 > 0.6f;
  bool has = p0 || p1 || p2;
  float mm = -__builtin_inff();
  if(p0) mm = fmaxf(mm, s01);
  if(p1) mm = fmaxf(mm, s02);
  if(p2) mm = fmaxf(mm, s12);
  if(!has) mm = 0.f;
  float q0 = p0 ? __expf(s01-mm) : 0.f;
  float q1 = p1 ? __expf(s02-mm) : 0.f;
  float q2 = p2 ? __expf(s12-mm) : 0.f;
  float rqs = __builtin_amdgcn_rcpf(fmaxf(q0+q1+q2, 1e-12f));
  float w0 = q0*rqs, w1 = q1*rqs, w2 = q2*rqs;

  u16x8 oc, ow;
  #pragma unroll
  for(int j=0;j<8;++j){
    float a = fb[j], b = ff[j], c = fp[j];
    float na = a*inb, nbv = b*invf, nc = c*inp;
    float c0 = (na*nbv > 0.6f) ? 0.5f*(a+b) : 0.f;
    float c1 = (na*nc  > 0.6f) ? 0.5f*(a+c) : 0.f;
    float c2 = (nbv*nc > 0.6f) ? 0.5f*(b+c) : 0.f;
    float sc = c0*w0 + c1*w1 + c2*w2;
    float cf = has ? sc : (a+b+c)*(1.f/3.f);
    float wv = a*fw0 + b*fw1 + c*fw2;
    oc[j] = f2b(cf); ow[j] = f2b(wv);
  }
  *(u16x8*)(common + base) = oc;       // in-place over ep
  *(u16x8*)(weighted + base) = ow;     // in-place over eb
}

extern "C" void kernel_launch(void* const* d_in, const int* in_sizes, int n_in,
                              void* d_out, int out_size, void* d_ws, size_t ws_size,
                              hipStream_t stream) {
  const float* brics = (const float*)d_in[0];
  const float* fg    = (const float*)d_in[1];
  const float* ph    = (const float*)d_in[2];
  const float* W1[3] = {(const float*)d_in[3], (const float*)d_in[7], (const float*)d_in[11]};
  const float* b1[3] = {(const float*)d_in[4], (const float*)d_in[8], (const float*)d_in[12]};
  const float* W2[3] = {(const float*)d_in[5], (const float*)d_in[9], (const float*)d_in[13]};
  const float* b2[3] = {(const float*)d_in[6], (const float*)d_in[10], (const float*)d_in[14]};
  const float* Wg = (const float*)d_in[15];
  const float* bg = (const float*)d_in[16];
  const float* We = (const float*)d_in[17];
  const float* be = (const float*)d_in[18];
  const float* Wf = (const float*)d_in[19];
  const float* bf = (const float*)d_in[20];
  float* out = (float*)d_out;

  const int M = in_sizes[0] / 256;   // 65536

  // ---- workspace carve ----
  char* wsp = (char*)d_ws;
  size_t off = 0;
  auto carve = [&](size_t elems)->u16* {
    u16* p = (u16*)(wsp + off);
    off += ((elems*sizeof(u16)) + 255) & ~(size_t)255;
    return p;
  };
  u16* xb0 = carve((size_t)M*256);   // enc0 (brics), then weighted (in-place)
  u16* xb1 = carve((size_t)M*256);   // enc1 (fg), then ce (gate out)
  u16* xb2 = carve((size_t)M*256);   // enc2 (ph), then common (in-place)
  u16* Wt1[3], *Wt2[3];
  for(int i=0;i<3;++i) Wt1[i] = carve(320*256);
  for(int i=0;i<3;++i) Wt2[i] = carve(256*320);
  u16* WtE = carve(256*256);
  u16* WtF = carve(256*512);         // full fused-output weight: [n=256][k=512]

  // hidden buffers: 3 separate if workspace allows (enables z-batched encoder GEMMs)
  size_t hb = (((size_t)M*320*sizeof(u16)) + 255) & ~(size_t)255;
  bool batched = (off + 3*hb) <= ws_size;
  u16* hh[3];
  hh[0] = (u16*)(wsp + off);
  hh[1] = batched ? (u16*)(wsp + off + hb)   : hh[0];
  hh[2] = batched ? (u16*)(wsp + off + 2*hb) : hh[0];
  (void)n_in; (void)out_size;

  // ---- 1. transpose/convert all weights ----
  TArgs ta;
  for(int i=0;i<3;++i){
    ta.p[i]   = {W1[i], Wt1[i], 256, 300, 256, 320};  // Wt1: [320][256]
    ta.p[3+i] = {W2[i], Wt2[i], 300, 256, 320, 256};  // Wt2: [256][320]
  }
  ta.p[6] = {We, WtE, 256, 256, 256, 256};
  ta.p[7] = {Wf, WtF, 512, 256, 512, 256};            // Wf: [512,256] -> WtF [256][512]
  transpose_all<<<dim3(512, 8), 256, 0, stream>>>(ta);

  // ---- 2. encoders: h_i = relu(x_i@W1+b1); enc_i = h_i@W2+b2 ----
  const float* xin[3] = {brics, fg, ph};
  u16* encp[3] = {xb0, xb1, xb2};
  if (batched) {
    GP g1{};
    for(int i=0;i<3;++i){ g1.A[i]=xin[i]; g1.Wt[i]=Wt1[i]; g1.bias[i]=b1[i]; g1.C[i]=hh[i]; }
    g1.lda=256; g1.K=256; g1.Nreal=300; g1.ldc=320;
    gemm_w<1,u16,float,false,5><<<dim3(M/128, 1, 3), 512, 0, stream>>>(g1);
    GP g2{};
    for(int i=0;i<3;++i){ g2.A[i]=hh[i]; g2.Wt[i]=Wt2[i]; g2.bias[i]=b2[i]; g2.C[i]=encp[i]; }
    g2.lda=320; g2.K=320; g2.Nreal=256; g2.ldc=256;
    gemm_w<0,u16,u16,false,4><<<dim3(M/128, 1, 3), 512, 0, stream>>>(g2);
  } else {
    for(int i=0;i<3;++i){
      GP g1{}; g1.A[0]=xin[i]; g1.Wt[0]=Wt1[i]; g1.bias[0]=b1[i]; g1.C[0]=hh[0];
      g1.lda=256; g1.K=256; g1.Nreal=300; g1.ldc=320;
      gemm_w<1,u16,float,false,5><<<dim3(M/128, 1, 1), 512, 0, stream>>>(g1);
      GP g2{}; g2.A[0]=hh[0]; g2.Wt[0]=Wt2[i]; g2.bias[0]=b2[i]; g2.C[0]=encp[i];
      g2.lda=320; g2.K=320; g2.Nreal=256; g2.ldc=256;
      gemm_w<0,u16,u16,false,4><<<dim3(M/128, 1, 1), 512, 0, stream>>>(g2);
    }
  }

  // ---- 3. row-wise middle: weighted -> xb0 (in place), common -> xb2 (in place) ----
  mid_k<<<M/8, 256, 0, stream>>>(xb0, xb1, xb2, Wg, bg, /*common=*/xb2, /*weighted=*/xb0);

  // ---- 4. gate: ce(xb1) = common * sigmoid(common@We + be) ----
  {
    GP gg{}; gg.A[0]=xb2; gg.Wt[0]=WtE; gg.bias[0]=be; gg.C[0]=xb1;
    gg.mult=xb2; gg.lda=256; gg.K=256; gg.Nreal=256; gg.ldc=256; gg.ldm=256;
    gemm_w<2,u16,u16,false,4><<<dim3(M/128, 1, 1), 512, 0, stream>>>(gg);
  }

  // ---- 5. fused output: out = [weighted | ce] @ WtF^T + bf  (single K=512 GEMM) ----
  {
    GP gf{}; gf.A[0]=xb0; gf.A2=xb1; gf.Wt[0]=WtF; gf.bias[0]=bf; gf.C[0]=out;
    gf.lda=256; gf.K=512; gf.Nreal=256; gf.ldc=256;
    gemm_w<0,float,u16,true,4><<<dim3(M/128, 1, 1), 512, 0, stream>>>(gf);
  }
}

// Round 6
// 434.443 us; speedup vs baseline: 1.2204x; 1.1451x over previous
//
#include <hip/hip_runtime.h>

typedef unsigned short u16;
typedef __bf16 bf16x8 __attribute__((ext_vector_type(8)));
typedef float f32x4 __attribute__((ext_vector_type(4)));
typedef unsigned short u16x8 __attribute__((ext_vector_type(8)));

__device__ __forceinline__ float b2f(u16 b){ union{unsigned u; float f;} v; v.u=((unsigned)b)<<16; return v.f; }
__device__ __forceinline__ u16 f2b(float f){ unsigned u=__builtin_bit_cast(unsigned,f); return (u16)((u+0x7fffu+((u>>16)&1u))>>16); }
__device__ __forceinline__ float wred32(float v){
  #pragma unroll
  for(int off=16; off>0; off>>=1) v += __shfl_xor(v, off, 64);  // halves stay independent
  return v;
}

// async global->LDS, 16B per lane: lane L writes ldsbase + L*16
__device__ __forceinline__ void gload_lds16(const void* g, void* l){
  __builtin_amdgcn_global_load_lds(
      (const __attribute__((address_space(1))) void*)g,
      (__attribute__((address_space(3))) void*)l, 16, 0, 0);
}

// stage a [ROWS x 64] bf16 tile via global_load_lds; LDS linear, source carries inverse XOR
// swizzle (elem col ^= (r&7)<<3) so ds_read with the same XOR is conflict-free.
// PER = ROWS*8/512 chunks per thread (512-thread block).
template<int PER>
__device__ __forceinline__ void stage_tile_b16(const u16* __restrict__ base, int rstride,
                                               int kcol, u16* lds, int w, int lane){
  #pragma unroll
  for(int it=0; it<PER; ++it){
    int cbase = it*512 + w*64;
    int ch = cbase + lane;
    int r = ch >> 3;
    int ce = ((ch & 7) * 8) ^ ((r & 7) << 3);
    gload_lds16(base + (size_t)r*rstride + kcol + ce, lds + cbase*8);
  }
}

// fp32 A tile: T14 async split. Issue loads early (into regs), convert+ds_write late.
struct Af32Regs { float4 a0, b0, a1, b1; };
__device__ __forceinline__ void loadA_f32(Af32Regs& rg, const float* __restrict__ Ap,
                                          int lda, int kcol, int tid){
  {
    int ch = tid;       int r = ch>>3, s = (ch&7)*8;
    const float* src = Ap + (size_t)r*lda + kcol + s;
    rg.a0 = *(const float4*)src; rg.b0 = *(const float4*)(src+4);
  }
  {
    int ch = tid + 512; int r = ch>>3, s = (ch&7)*8;
    const float* src = Ap + (size_t)r*lda + kcol + s;
    rg.a1 = *(const float4*)src; rg.b1 = *(const float4*)(src+4);
  }
}
__device__ __forceinline__ void writeA_f32(const Af32Regs& rg, u16* As, int tid){
  {
    int ch = tid;       int r = ch>>3, s = (ch&7)*8;
    u16* dst = &As[r*64 + (s ^ ((r&7)<<3))];
    ushort4 o0{f2b(rg.a0.x),f2b(rg.a0.y),f2b(rg.a0.z),f2b(rg.a0.w)};
    ushort4 o1{f2b(rg.b0.x),f2b(rg.b0.y),f2b(rg.b0.z),f2b(rg.b0.w)};
    *(ushort4*)dst = o0; *(ushort4*)(dst+4) = o1;
  }
  {
    int ch = tid + 512; int r = ch>>3, s = (ch&7)*8;
    u16* dst = &As[r*64 + (s ^ ((r&7)<<3))];
    ushort4 o0{f2b(rg.a1.x),f2b(rg.a1.y),f2b(rg.a1.z),f2b(rg.a1.w)};
    ushort4 o1{f2b(rg.b1.x),f2b(rg.b1.y),f2b(rg.b1.z),f2b(rg.b1.w)};
    *(ushort4*)dst = o0; *(ushort4*)(dst+4) = o1;
  }
}

// ---------------- wide MFMA GEMM, z-batched: C_z[M, BN] = act(A_z[M,K] @ Wt_z^T + bias_z) ----
// One block covers the FULL N (BN = NWT*64): A fetched exactly once.
// 512 threads = 8 waves (2 row x 4 col). Double-buffered LDS, prefetch issued before MFMA.
// Epilogue: acc -> LDS transpose -> u16x8 full-line stores (kills write-allocate amp).
// MODE 0: +bias. MODE 1: relu(+bias). Output u16 (bf16).
struct GP {
  const void* A[3];
  const u16*  Wt[3];
  const float* bias[3];
  void* C[3];
  int lda, K, Nreal, ldc;
};

template<int MODE, typename AT, int NWT>
__global__ __launch_bounds__(512, 2) void gemm_w(GP p)
{
  constexpr int BN = NWT*64;
  constexpr int AHALF = 128*64;
  constexpr int BHALF = BN*64;
  __shared__ __align__(16) u16 smem[2*AHALF + 2*BHALF];

  const int z = blockIdx.z;
  const AT* __restrict__ A  = (const AT*)p.A[z];
  const u16* __restrict__ Wt = p.Wt[z];
  const float* __restrict__ bias = p.bias[z];
  u16* __restrict__ C = (u16*)p.C[z];
  const int lda = p.lda, K = p.K, ldc = p.ldc;

  const int tid = threadIdx.x;
  const size_t m0 = (size_t)blockIdx.x * 128;
  const int lane = tid & 63, w = tid >> 6;
  const int lr = lane & 15, quad = lane >> 4;
  const int wr = (w >> 2) * 64, wc = (w & 3) * (NWT*16);
  const int swz = (lr & 7) << 3;
  const int NT = K >> 6;

  f32x4 acc[4][NWT];
  #pragma unroll
  for(int i=0;i<4;++i)
    #pragma unroll
    for(int j=0;j<NWT;++j) acc[i][j] = (f32x4){0.f,0.f,0.f,0.f};

  const AT* Ab = A + m0*(size_t)lda;

  // prologue: stage tile 0 into buf 0
  if constexpr (__is_same(AT, u16)) {
    stage_tile_b16<2>((const u16*)Ab, lda, 0, smem, w, lane);
  } else {
    Af32Regs rg; loadA_f32(rg, (const float*)Ab, lda, 0, tid);
    writeA_f32(rg, smem, tid);
  }
  stage_tile_b16<NWT>(Wt, K, 0, smem + 2*AHALF, w, lane);
  __syncthreads();

  int cur = 0;
  for(int t=0; t<NT; ++t){
    const int knext = (t+1) << 6;
    const bool pf = (t+1) < NT;
    Af32Regs rg;
    if (pf){
      if constexpr (__is_same(AT, u16))
        stage_tile_b16<2>((const u16*)Ab, lda, knext, smem + (cur^1)*AHALF, w, lane);
      else
        loadA_f32(rg, (const float*)Ab, lda, knext, tid);   // issue early; write after MFMA
      stage_tile_b16<NWT>(Wt, K, knext, smem + 2*AHALF + (cur^1)*BHALF, w, lane);
    }
    const u16* Asc = smem + cur*AHALF;
    const u16* Bsc = smem + 2*AHALF + cur*BHALF;
    #pragma unroll
    for(int kk=0; kk<64; kk+=32){
      bf16x8 af[4], bq[NWT];
      #pragma unroll
      for(int i=0;i<4;++i)
        af[i] = *(const bf16x8*)&Asc[(wr + i*16 + lr)*64 + ((kk + quad*8) ^ swz)];
      #pragma unroll
      for(int j=0;j<NWT;++j)
        bq[j] = *(const bf16x8*)&Bsc[(wc + j*16 + lr)*64 + ((kk + quad*8) ^ swz)];
      #pragma unroll
      for(int i=0;i<4;++i)
        #pragma unroll
        for(int j=0;j<NWT;++j)
          acc[i][j] = __builtin_amdgcn_mfma_f32_16x16x32_bf16(af[i], bq[j], acc[i][j], 0, 0, 0);
    }
    if constexpr (!__is_same(AT, u16)) { if (pf) writeA_f32(rg, smem + (cur^1)*AHALF, tid); }
    __syncthreads();
    cur ^= 1;
  }

  // ---- epilogue: bias/act -> Ct (LDS, padded) -> vectorized u16x8 stores ----
  constexpr int BNP = BN + 8;
  static_assert(128*BNP <= 2*AHALF + 2*BHALF, "Ct fits in smem");
  u16* Ct = smem;
  #pragma unroll
  for(int j=0;j<NWT;++j){
    int col = wc + j*16 + lr;
    float bv = (col < p.Nreal) ? bias[col] : 0.f;
    #pragma unroll
    for(int i=0;i<4;++i){
      #pragma unroll
      for(int r=0;r<4;++r){
        float v = acc[i][j][r] + bv;
        if(MODE==1) v = fmaxf(v, 0.f);
        Ct[(wr + i*16 + quad*4 + r)*BNP + col] = f2b(v);
      }
    }
  }
  __syncthreads();
  const int rowg = tid >> 2, cg = tid & 3;
  const size_t crow = (m0 + rowg)*(size_t)ldc;
  #pragma unroll
  for(int k2=0; k2<BN/32; ++k2){
    int c = (cg + k2*4)*8;
    *(u16x8*)&C[crow + c] = *(const u16x8*)&Ct[rowg*BNP + c];
  }
}

// ---------------- weight pre-transpose fp32->bf16 (+zero pad): dst[n*Kp+k] = src[k*N+n]
struct TPar { const float* src; u16* dst; int K, N, Kp, Np; };
struct TArgs { TPar p[8]; };
__global__ __launch_bounds__(256) void transpose_all(TArgs args){
  TPar p = args.p[blockIdx.y];
  int n = blockIdx.x;
  if (n >= p.Np) return;
  for (int k = threadIdx.x; k < p.Kp; k += 256){
    u16 v = 0;
    if (n < p.N && k < p.K) v = f2b(p.src[(size_t)k*p.N + n]);
    p.dst[(size_t)n*p.Kp + k] = v;
  }
}

// ---------------- fused tail: mid (norms/sims/gates) + gate GEMM + final GEMM ----------------
// One block = 64 rows. 512 threads = 8 waves (2 row-groups x 4 col-groups).
// LDS: cw (common->ce) 32KB + ww (weighted) 32KB, both as 4 k-chunks [64][64] XOR-swizzled;
//      Bst dbuf 2x[256][64] = 64KB staged from L2.
__global__ __launch_bounds__(512, 2) void fuse3_k(
    const u16* __restrict__ eb, const u16* __restrict__ ef, const u16* __restrict__ ep,
    const float* __restrict__ Wg, const float* __restrict__ bg,
    const u16* __restrict__ WtE, const float* __restrict__ be,
    const u16* __restrict__ WtF, const float* __restrict__ bfv,
    float* __restrict__ out)
{
  constexpr int BHALF = 256*64;
  __shared__ __align__(16) u16 cw[4*64*64];
  __shared__ __align__(16) u16 ww[4*64*64];
  __shared__ __align__(16) u16 Bst[2*BHALF];

  const int tid = threadIdx.x;
  const size_t m0 = (size_t)blockIdx.x * 64;
  const int lane = tid & 63, w = tid >> 6;
  const int lr = lane & 15, quad = lane >> 4;
  const int wr = (w >> 2) * 32, wc = (w & 3) * 64;
  const int swz = (lr & 7) << 3;

  // prefetch gate-weight chunk 0 while mid runs (drained by the barrier before the gate loop)
  stage_tile_b16<4>(WtE, 256, 0, Bst, w, lane);

  // ---- mid phase: 4 passes x 16 rows; 32 lanes x 8 elems per row ----
  const int rid = tid >> 5, l5 = tid & 31;
  for(int pass=0; pass<4; ++pass){
    int rloc = pass*16 + rid;
    size_t base = (m0 + rloc)*256 + l5*8;

    u16x8 vb = *(const u16x8*)(eb + base);
    u16x8 vf = *(const u16x8*)(ef + base);
    u16x8 vp = *(const u16x8*)(ep + base);
    float fb[8], ff[8], fp[8];
    #pragma unroll
    for(int j=0;j<8;++j){ fb[j]=b2f(vb[j]); ff[j]=b2f(vf[j]); fp[j]=b2f(vp[j]); }

    float sb=0, sf=0, sp=0, d01=0, d02=0, d12=0, g0=0, g1=0, g2=0;
    #pragma unroll
    for(int j=0;j<8;++j){
      sb += fb[j]*fb[j]; sf += ff[j]*ff[j]; sp += fp[j]*fp[j];
      d01 += fb[j]*ff[j]; d02 += fb[j]*fp[j]; d12 += ff[j]*fp[j];
    }
    #pragma unroll
    for(int seg=0; seg<3; ++seg){
      const float* x = (seg==0) ? fb : (seg==1) ? ff : fp;
      const float* wg = Wg + ((size_t)seg*256 + l5*8)*3;
      float wv[24];
      #pragma unroll
      for(int q=0;q<6;++q){
        float4 t = *(const float4*)(wg + q*4);
        wv[q*4+0]=t.x; wv[q*4+1]=t.y; wv[q*4+2]=t.z; wv[q*4+3]=t.w;
      }
      #pragma unroll
      for(int j=0;j<8;++j){
        g0 += x[j]*wv[j*3+0];
        g1 += x[j]*wv[j*3+1];
        g2 += x[j]*wv[j*3+2];
      }
    }
    sb=wred32(sb); sf=wred32(sf); sp=wred32(sp);
    d01=wred32(d01); d02=wred32(d02); d12=wred32(d12);
    g0=wred32(g0); g1=wred32(g1); g2=wred32(g2);

    float inb  = __builtin_amdgcn_rsqf(fmaxf(sb, 1e-24f));
    float invf = __builtin_amdgcn_rsqf(fmaxf(sf, 1e-24f));
    float inp  = __builtin_amdgcn_rsqf(fmaxf(sp, 1e-24f));
    float s01 = d01*inb*invf, s02 = d02*inb*inp, s12 = d12*invf*inp;

    float h0 = g0 + bg[0], h1 = g1 + bg[1], h2 = g2 + bg[2];
    float gm = fmaxf(h0, fmaxf(h1, h2));
    float e0 = __expf(h0-gm), e1 = __expf(h1-gm), e2 = __expf(h2-gm);
    float res = __builtin_amdgcn_rcpf(e0+e1+e2);
    float fw0 = e0*res, fw1 = e1*res, fw2 = e2*res;

    bool p0 = s01 > 0.6f, p1 = s02 > 0.6f, p2 = s12 > 0.6f;
    bool has = p0 || p1 || p2;
    float mm = -__builtin_inff();
    if(p0) mm = fmaxf(mm, s01);
    if(p1) mm = fmaxf(mm, s02);
    if(p2) mm = fmaxf(mm, s12);
    if(!has) mm = 0.f;
    float q0 = p0 ? __expf(s01-mm) : 0.f;
    float q1 = p1 ? __expf(s02-mm) : 0.f;
    float q2 = p2 ? __expf(s12-mm) : 0.f;
    float rqs = __builtin_amdgcn_rcpf(fmaxf(q0+q1+q2, 1e-12f));
    float w0 = q0*rqs, w1 = q1*rqs, w2 = q2*rqs;

    u16x8 oc, ow;
    #pragma unroll
    for(int j=0;j<8;++j){
      float a = fb[j], b = ff[j], c = fp[j];
      float na = a*inb, nbv = b*invf, nc = c*inp;
      float c0 = (na*nbv > 0.6f) ? 0.5f*(a+b) : 0.f;
      float c1 = (na*nc  > 0.6f) ? 0.5f*(a+c) : 0.f;
      float c2 = (nbv*nc > 0.6f) ? 0.5f*(b+c) : 0.f;
      float sc = c0*w0 + c1*w1 + c2*w2;
      float cf = has ? sc : (a+b+c)*(1.f/3.f);
      float wv = a*fw0 + b*fw1 + c*fw2;
      oc[j] = f2b(cf); ow[j] = f2b(wv);
    }
    // swizzled LDS write: chunk = l5>>3, within = (l5&7)*8
    int idx = (l5>>3)*4096 + rloc*64 + (((l5&7)*8) ^ ((rloc&7)<<3));
    *(u16x8*)&cw[idx] = oc;
    *(u16x8*)&ww[idx] = ow;
  }
  __syncthreads();   // mid done + WtE chunk0 staged (vmcnt drained)

  // ---- gate GEMM: ga = common @ WtE^T ; K=256 (4 chunks) ----
  f32x4 ga[2][4];
  #pragma unroll
  for(int i=0;i<2;++i)
    #pragma unroll
    for(int j=0;j<4;++j) ga[i][j] = (f32x4){0.f,0.f,0.f,0.f};

  int cur = 0;
  for(int t=0; t<4; ++t){
    if(t<3) stage_tile_b16<4>(WtE, 256, (t+1)*64, Bst + (cur^1)*BHALF, w, lane);
    const u16* Asc = cw + t*4096;
    const u16* Bsc = Bst + cur*BHALF;
    #pragma unroll
    for(int kk=0; kk<64; kk+=32){
      bf16x8 af[2], bq[4];
      #pragma unroll
      for(int i=0;i<2;++i)
        af[i] = *(const bf16x8*)&Asc[(wr + i*16 + lr)*64 + ((kk + quad*8) ^ swz)];
      #pragma unroll
      for(int j=0;j<4;++j)
        bq[j] = *(const bf16x8*)&Bsc[(wc + j*16 + lr)*64 + ((kk + quad*8) ^ swz)];
      #pragma unroll
      for(int i=0;i<2;++i)
        #pragma unroll
        for(int j=0;j<4;++j)
          ga[i][j] = __builtin_amdgcn_mfma_f32_16x16x32_bf16(af[i], bq[j], ga[i][j], 0, 0, 0);
    }
    __syncthreads();
    cur ^= 1;
  }
  // cur == 0 here. Prefetch final-weight chunk 0 into buf 0 (free), overlap with epilogue.
  stage_tile_b16<4>(WtF, 512, 0, Bst, w, lane);

  // gate epilogue: ce = common * sigmoid(ga + be), written in-place over cw.
  // Each (row,col) element is owned by exactly one thread: read-then-write is race-free.
  #pragma unroll
  for(int j=0;j<4;++j){
    int col = wc + j*16 + lr;
    float bev = be[col];
    int within = j*16 + lr;
    #pragma unroll
    for(int i=0;i<2;++i){
      #pragma unroll
      for(int r=0;r<4;++r){
        int rl = wr + i*16 + quad*4 + r;
        int idx = (w & 3)*4096 + rl*64 + (within ^ ((rl&7)<<3));
        float cv = b2f(cw[idx]);
        float v = ga[i][j][r] + bev;
        cw[idx] = f2b(cv * __builtin_amdgcn_rcpf(1.f + __expf(-v)));
      }
    }
  }
  __syncthreads();   // ce visible + WtF chunk0 staged

  // ---- final GEMM: fa = [weighted | ce] @ WtF^T ; K=512 (8 chunks: ww then cw) ----
  f32x4 fa[2][4];
  #pragma unroll
  for(int i=0;i<2;++i)
    #pragma unroll
    for(int j=0;j<4;++j) fa[i][j] = (f32x4){0.f,0.f,0.f,0.f};

  cur = 0;
  for(int t=0; t<8; ++t){
    if(t<7) stage_tile_b16<4>(WtF, 512, (t+1)*64, Bst + (cur^1)*BHALF, w, lane);
    const u16* Asc = (t < 4) ? (ww + t*4096) : (cw + (t-4)*4096);
    const u16* Bsc = Bst + cur*BHALF;
    #pragma unroll
    for(int kk=0; kk<64; kk+=32){
      bf16x8 af[2], bq[4];
      #pragma unroll
      for(int i=0;i<2;++i)
        af[i] = *(const bf16x8*)&Asc[(wr + i*16 + lr)*64 + ((kk + quad*8) ^ swz)];
      #pragma unroll
      for(int j=0;j<4;++j)
        bq[j] = *(const bf16x8*)&Bsc[(wc + j*16 + lr)*64 + ((kk + quad*8) ^ swz)];
      #pragma unroll
      for(int i=0;i<2;++i)
        #pragma unroll
        for(int j=0;j<4;++j)
          fa[i][j] = __builtin_amdgcn_mfma_f32_16x16x32_bf16(af[i], bq[j], fa[i][j], 0, 0, 0);
    }
    __syncthreads();
    cur ^= 1;
  }

  // final epilogue: fp32 stores; each instr covers 16 cols x 4B = full 64B segments.
  #pragma unroll
  for(int j=0;j<4;++j){
    int col = wc + j*16 + lr;
    float bfc = bfv[col];
    #pragma unroll
    for(int i=0;i<2;++i){
      #pragma unroll
      for(int r=0;r<4;++r){
        size_t row = m0 + wr + i*16 + quad*4 + r;
        out[row*256 + col] = fa[i][j][r] + bfc;
      }
    }
  }
}

extern "C" void kernel_launch(void* const* d_in, const int* in_sizes, int n_in,
                              void* d_out, int out_size, void* d_ws, size_t ws_size,
                              hipStream_t stream) {
  const float* brics = (const float*)d_in[0];
  const float* fg    = (const float*)d_in[1];
  const float* ph    = (const float*)d_in[2];
  const float* W1[3] = {(const float*)d_in[3], (const float*)d_in[7], (const float*)d_in[11]};
  const float* b1[3] = {(const float*)d_in[4], (const float*)d_in[8], (const float*)d_in[12]};
  const float* W2[3] = {(const float*)d_in[5], (const float*)d_in[9], (const float*)d_in[13]};
  const float* b2[3] = {(const float*)d_in[6], (const float*)d_in[10], (const float*)d_in[14]};
  const float* Wg = (const float*)d_in[15];
  const float* bg = (const float*)d_in[16];
  const float* We = (const float*)d_in[17];
  const float* be = (const float*)d_in[18];
  const float* Wf = (const float*)d_in[19];
  const float* bf = (const float*)d_in[20];
  float* out = (float*)d_out;

  const int M = in_sizes[0] / 256;   // 65536

  // ---- workspace carve ----
  char* wsp = (char*)d_ws;
  size_t off = 0;
  auto carve = [&](size_t elems)->u16* {
    u16* p = (u16*)(wsp + off);
    off += ((elems*sizeof(u16)) + 255) & ~(size_t)255;
    return p;
  };
  u16* xb0 = carve((size_t)M*256);   // enc0 (brics)
  u16* xb1 = carve((size_t)M*256);   // enc1 (fg)
  u16* xb2 = carve((size_t)M*256);   // enc2 (ph)
  u16* Wt1[3], *Wt2[3];
  for(int i=0;i<3;++i) Wt1[i] = carve(320*256);
  for(int i=0;i<3;++i) Wt2[i] = carve(256*320);
  u16* WtE = carve(256*256);
  u16* WtF = carve(256*512);         // fused-output weight: [n=256][k=512]

  // hidden buffers: 3 separate if workspace allows (enables z-batched encoder GEMMs)
  size_t hb = (((size_t)M*320*sizeof(u16)) + 255) & ~(size_t)255;
  bool batched = (off + 3*hb) <= ws_size;
  u16* hh[3];
  hh[0] = (u16*)(wsp + off);
  hh[1] = batched ? (u16*)(wsp + off + hb)   : hh[0];
  hh[2] = batched ? (u16*)(wsp + off + 2*hb) : hh[0];
  (void)n_in; (void)out_size;

  // ---- 1. transpose/convert all weights ----
  TArgs ta;
  for(int i=0;i<3;++i){
    ta.p[i]   = {W1[i], Wt1[i], 256, 300, 256, 320};  // Wt1: [320][256]
    ta.p[3+i] = {W2[i], Wt2[i], 300, 256, 320, 256};  // Wt2: [256][320]
  }
  ta.p[6] = {We, WtE, 256, 256, 256, 256};
  ta.p[7] = {Wf, WtF, 512, 256, 512, 256};            // Wf: [512,256] -> WtF [256][512]
  transpose_all<<<dim3(512, 8), 256, 0, stream>>>(ta);

  // ---- 2. encoders: h_i = relu(x_i@W1+b1); enc_i = h_i@W2+b2 ----
  const float* xin[3] = {brics, fg, ph};
  u16* encp[3] = {xb0, xb1, xb2};
  if (batched) {
    GP g1{};
    for(int i=0;i<3;++i){ g1.A[i]=xin[i]; g1.Wt[i]=Wt1[i]; g1.bias[i]=b1[i]; g1.C[i]=hh[i]; }
    g1.lda=256; g1.K=256; g1.Nreal=300; g1.ldc=320;
    gemm_w<1,float,5><<<dim3(M/128, 1, 3), 512, 0, stream>>>(g1);
    GP g2{};
    for(int i=0;i<3;++i){ g2.A[i]=hh[i]; g2.Wt[i]=Wt2[i]; g2.bias[i]=b2[i]; g2.C[i]=encp[i]; }
    g2.lda=320; g2.K=320; g2.Nreal=256; g2.ldc=256;
    gemm_w<0,u16,4><<<dim3(M/128, 1, 3), 512, 0, stream>>>(g2);
  } else {
    for(int i=0;i<3;++i){
      GP g1{}; g1.A[0]=xin[i]; g1.Wt[0]=Wt1[i]; g1.bias[0]=b1[i]; g1.C[0]=hh[0];
      g1.lda=256; g1.K=256; g1.Nreal=300; g1.ldc=320;
      gemm_w<1,float,5><<<dim3(M/128, 1, 1), 512, 0, stream>>>(g1);
      GP g2{}; g2.A[0]=hh[0]; g2.Wt[0]=Wt2[i]; g2.bias[0]=b2[i]; g2.C[0]=encp[i];
      g2.lda=320; g2.K=320; g2.Nreal=256; g2.ldc=256;
      gemm_w<0,u16,4><<<dim3(M/128, 1, 1), 512, 0, stream>>>(g2);
    }
  }

  // ---- 3. fused tail: mid + gate + final -> out ----
  fuse3_k<<<M/64, 512, 0, stream>>>(xb0, xb1, xb2, Wg, bg, WtE, be, WtF, bf, out);
}